// Round 1
// baseline (2915.575 us; speedup 1.0000x reference)
//
#include <hip/hip_runtime.h>
#include <math.h>

#define DEV __device__ __forceinline__

// ---------------------------------------------------------------------------
// Register-blocked GEMM tile: 32 rows x 128 cols per 256-thread block.
// Thread (tr = tid>>5 in [0,8), tc = tid&31) computes rows tr*4..tr*4+3,
// cols c0 + tc*4 .. +3.  KDIM must be a multiple of 4.  inLds rows are
// LDIN floats (LDIN multiple of 4, base 16B aligned).
// ---------------------------------------------------------------------------
template<int KDIM, int LDIN, int WSTRIDE>
DEV void gemm_tile(const float* inLds, const float* __restrict__ W,
                   const float* __restrict__ b, int c0, int tid,
                   float (&acc)[4][4])
{
    const int tc  = tid & 31;
    const int tr  = tid >> 5;
    const int col = c0 + tc * 4;
#pragma unroll
    for (int jj = 0; jj < 4; ++jj) {
        const float bv = b[col + jj];
#pragma unroll
        for (int rr = 0; rr < 4; ++rr) acc[rr][jj] = bv;
    }
#pragma unroll 2
    for (int k = 0; k < KDIM; k += 4) {
        const float4 w0 = *(const float4*)&W[(size_t)(k + 0) * WSTRIDE + col];
        const float4 w1 = *(const float4*)&W[(size_t)(k + 1) * WSTRIDE + col];
        const float4 w2 = *(const float4*)&W[(size_t)(k + 2) * WSTRIDE + col];
        const float4 w3 = *(const float4*)&W[(size_t)(k + 3) * WSTRIDE + col];
#pragma unroll
        for (int rr = 0; rr < 4; ++rr) {
            const float4 f = *(const float4*)&inLds[(size_t)(tr * 4 + rr) * LDIN + k];
            acc[rr][0] = fmaf(f.x, w0.x, acc[rr][0]);
            acc[rr][1] = fmaf(f.x, w0.y, acc[rr][1]);
            acc[rr][2] = fmaf(f.x, w0.z, acc[rr][2]);
            acc[rr][3] = fmaf(f.x, w0.w, acc[rr][3]);
            acc[rr][0] = fmaf(f.y, w1.x, acc[rr][0]);
            acc[rr][1] = fmaf(f.y, w1.y, acc[rr][1]);
            acc[rr][2] = fmaf(f.y, w1.z, acc[rr][2]);
            acc[rr][3] = fmaf(f.y, w1.w, acc[rr][3]);
            acc[rr][0] = fmaf(f.z, w2.x, acc[rr][0]);
            acc[rr][1] = fmaf(f.z, w2.y, acc[rr][1]);
            acc[rr][2] = fmaf(f.z, w2.z, acc[rr][2]);
            acc[rr][3] = fmaf(f.z, w2.w, acc[rr][3]);
            acc[rr][0] = fmaf(f.w, w3.x, acc[rr][0]);
            acc[rr][1] = fmaf(f.w, w3.y, acc[rr][1]);
            acc[rr][2] = fmaf(f.w, w3.z, acc[rr][2]);
            acc[rr][3] = fmaf(f.w, w3.w, acc[rr][3]);
        }
    }
}

// ---------------------------------------------------------------------------
// Pad eW1 [EIN][128] -> [EINP][128] with zero rows (so GEMM K-loop can be x4).
// ---------------------------------------------------------------------------
__global__ void pad_w1_kernel(const float* __restrict__ W, float* __restrict__ Wp,
                              int EIN, int EINP)
{
    const int i = blockIdx.x * 256 + threadIdx.x;
    if (i < EINP * 128) {
        const int k = i >> 7;   // /128
        const int j = i & 127;
        Wp[i] = (k < EIN) ? W[k * 128 + j] : 0.0f;
    }
}

// ---------------------------------------------------------------------------
// Edge conv: build feat = [xi, xj-xi, xj*xi, |d|, <xj,xi>, ea] per edge,
// m = relu(relu(feat@W1+b1)@W2+b2), segment_max into agg[dst] via atomicMax.
// 32 edges per block.
// ---------------------------------------------------------------------------
template<int FIN, int EIN, int EINP>
__global__ __launch_bounds__(256)
void edge_conv_kernel(const float* __restrict__ x,
                      const int* __restrict__ srcIdx, const int* __restrict__ dstIdx,
                      const float* __restrict__ ea,
                      const float* __restrict__ W1p, const float* __restrict__ b1,
                      const float* __restrict__ W2,  const float* __restrict__ b2,
                      float* __restrict__ agg, int E)
{
    __shared__ __align__(16) float feat[32][EINP];
    __shared__ __align__(16) float h1[32][128];
    const int tid = threadIdx.x;
    const int e0  = blockIdx.x * 32;

    // --- stage 1: gather + feature construction (8 threads per edge) ---
    {
        const int r = tid >> 3;
        const int s = tid & 7;
        const int e = e0 + r;
        if (e < E) {
            const int si = srcIdx[e];
            const int di = dstIdx[e];
            const float* xs = x + (size_t)si * FIN;
            const float* xd = x + (size_t)di * FIN;
            float sd2 = 0.0f, sp = 0.0f;
#pragma unroll
            for (int d = s; d < FIN; d += 8) {
                const float vj = xs[d];
                const float vi = xd[d];
                const float dd = vj - vi;
                const float pp = vj * vi;
                feat[r][d]           = vi;
                feat[r][FIN + d]     = dd;
                feat[r][2 * FIN + d] = pp;
                sd2 += dd * dd;
                sp  += pp;
            }
            sd2 += __shfl_down(sd2, 4, 8);  sp += __shfl_down(sp, 4, 8);
            sd2 += __shfl_down(sd2, 2, 8);  sp += __shfl_down(sp, 2, 8);
            sd2 += __shfl_down(sd2, 1, 8);  sp += __shfl_down(sp, 1, 8);
            if (s == 0) {
                feat[r][3 * FIN]     = sqrtf(sd2);
                feat[r][3 * FIN + 1] = sp;
            }
            if (s < 4) feat[r][3 * FIN + 2 + s] = ea[(size_t)e * 4 + s];
            for (int d = EIN + s; d < EINP; d += 8) feat[r][d] = 0.0f;
        } else {
            for (int d = s; d < EINP; d += 8) feat[r][d] = 0.0f;
        }
    }
    __syncthreads();

    float acc[4][4];
    // --- stage 2: h1 = relu(feat @ W1 + b1) ---
    gemm_tile<EINP, EINP, 128>(&feat[0][0], W1p, b1, 0, tid, acc);
    {
        const int tc = tid & 31, tr = tid >> 5;
#pragma unroll
        for (int rr = 0; rr < 4; ++rr) {
            float4 v;
            v.x = fmaxf(acc[rr][0], 0.0f);
            v.y = fmaxf(acc[rr][1], 0.0f);
            v.z = fmaxf(acc[rr][2], 0.0f);
            v.w = fmaxf(acc[rr][3], 0.0f);
            *(float4*)&h1[tr * 4 + rr][tc * 4] = v;
        }
    }
    __syncthreads();
    // --- stage 3: m = relu(h1 @ W2 + b2); atomicMax into agg[dst] ---
    gemm_tile<128, 128, 128>(&h1[0][0], W2, b2, 0, tid, acc);
    {
        const int tc = tid & 31, tr = tid >> 5;
#pragma unroll
        for (int rr = 0; rr < 4; ++rr) {
            const int e = e0 + tr * 4 + rr;
            if (e < E) {
                const int di = dstIdx[e];
                int* dp = (int*)(agg + (size_t)di * 128 + tc * 4);
#pragma unroll
                for (int jj = 0; jj < 4; ++jj) {
                    const float v = fmaxf(acc[rr][jj], 0.0f);
                    atomicMax(dp + jj, __float_as_int(v));  // v>=0: int order == float order
                }
            }
        }
    }
}

// ---------------------------------------------------------------------------
// Node MLP: y = relu(relu([x, agg]@W1+b1)@W2+b2) (+x if RES). 32 nodes/block.
// ---------------------------------------------------------------------------
template<int FIN, bool RES>
__global__ __launch_bounds__(256)
void node_kernel(const float* __restrict__ xin, const float* __restrict__ agg,
                 const float* __restrict__ W1, const float* __restrict__ b1,
                 const float* __restrict__ W2, const float* __restrict__ b2,
                 float* __restrict__ out, int N)
{
    constexpr int K1 = FIN + 128;
    __shared__ __align__(16) float inb[32][K1];
    __shared__ __align__(16) float h1[32][128];
    const int tid = threadIdx.x;
    const int n0  = blockIdx.x * 32;
    {
        const int r = tid >> 3;
        const int s = tid & 7;
        const int n = n0 + r;
        if (n < N) {
            for (int d = s; d < FIN; d += 8) inb[r][d] = xin[(size_t)n * FIN + d];
            for (int d = s; d < 128; d += 8) inb[r][FIN + d] = agg[(size_t)n * 128 + d];
        } else {
            for (int d = s; d < K1; d += 8) inb[r][d] = 0.0f;
        }
    }
    __syncthreads();

    float acc[4][4];
    gemm_tile<K1, K1, 128>(&inb[0][0], W1, b1, 0, tid, acc);
    {
        const int tc = tid & 31, tr = tid >> 5;
#pragma unroll
        for (int rr = 0; rr < 4; ++rr) {
            float4 v;
            v.x = fmaxf(acc[rr][0], 0.0f);
            v.y = fmaxf(acc[rr][1], 0.0f);
            v.z = fmaxf(acc[rr][2], 0.0f);
            v.w = fmaxf(acc[rr][3], 0.0f);
            *(float4*)&h1[tr * 4 + rr][tc * 4] = v;
        }
    }
    __syncthreads();
    gemm_tile<128, 128, 128>(&h1[0][0], W2, b2, 0, tid, acc);
    {
        const int tc = tid & 31, tr = tid >> 5;
#pragma unroll
        for (int rr = 0; rr < 4; ++rr) {
            const int n = n0 + tr * 4 + rr;
            if (n < N) {
                const int col = tc * 4;
#pragma unroll
                for (int jj = 0; jj < 4; ++jj) {
                    float v = fmaxf(acc[rr][jj], 0.0f);
                    if (RES) v += xin[(size_t)n * 128 + col + jj];
                    out[(size_t)n * 128 + col + jj] = v;
                }
            }
        }
    }
}

// ---------------------------------------------------------------------------
// Fusion MLP: out = relu(relu([x1,x2,x3]@W1+b1)@W2+b2). 32 nodes/block.
// W1: [384][256], W2: [256][128].
// ---------------------------------------------------------------------------
__global__ __launch_bounds__(256)
void fusion_kernel(const float* __restrict__ x1, const float* __restrict__ x2,
                   const float* __restrict__ x3,
                   const float* __restrict__ W1, const float* __restrict__ b1,
                   const float* __restrict__ W2, const float* __restrict__ b2,
                   float* __restrict__ out, int N)
{
    __shared__ __align__(16) float inb[32][384];
    __shared__ __align__(16) float h1[32][256];
    const int tid = threadIdx.x;
    const int n0  = blockIdx.x * 32;
    {
        const int r = tid >> 3;
        const int s = tid & 7;
        const int n = n0 + r;
        if (n < N) {
            for (int d = s; d < 128; d += 8) {
                inb[r][d]       = x1[(size_t)n * 128 + d];
                inb[r][128 + d] = x2[(size_t)n * 128 + d];
                inb[r][256 + d] = x3[(size_t)n * 128 + d];
            }
        } else {
            for (int d = s; d < 384; d += 8) inb[r][d] = 0.0f;
        }
    }
    __syncthreads();

    float acc[4][4];
#pragma unroll
    for (int c0 = 0; c0 < 256; c0 += 128) {
        gemm_tile<384, 384, 256>(&inb[0][0], W1, b1, c0, tid, acc);
        const int tc = tid & 31, tr = tid >> 5;
#pragma unroll
        for (int rr = 0; rr < 4; ++rr) {
            float4 v;
            v.x = fmaxf(acc[rr][0], 0.0f);
            v.y = fmaxf(acc[rr][1], 0.0f);
            v.z = fmaxf(acc[rr][2], 0.0f);
            v.w = fmaxf(acc[rr][3], 0.0f);
            *(float4*)&h1[tr * 4 + rr][c0 + tc * 4] = v;
        }
    }
    __syncthreads();
    gemm_tile<256, 256, 128>(&h1[0][0], W2, b2, 0, tid, acc);
    {
        const int tc = tid & 31, tr = tid >> 5;
#pragma unroll
        for (int rr = 0; rr < 4; ++rr) {
            const int n = n0 + tr * 4 + rr;
            if (n < N) {
#pragma unroll
                for (int jj = 0; jj < 4; ++jj)
                    out[(size_t)n * 128 + tc * 4 + jj] = fmaxf(acc[rr][jj], 0.0f);
            }
        }
    }
}

// ---------------------------------------------------------------------------
extern "C" void kernel_launch(void* const* d_in, const int* in_sizes, int n_in,
                              void* d_out, int out_size, void* d_ws, size_t ws_size,
                              hipStream_t stream)
{
    const float* x    = (const float*)d_in[0];
    const int*   eidx = (const int*)d_in[1];
    const float* ea   = (const float*)d_in[2];

    const float* c1_eW1 = (const float*)d_in[3];
    const float* c1_eb1 = (const float*)d_in[4];
    const float* c1_eW2 = (const float*)d_in[5];
    const float* c1_eb2 = (const float*)d_in[6];
    const float* c1_lW1 = (const float*)d_in[7];
    const float* c1_lb1 = (const float*)d_in[8];
    const float* c1_lW2 = (const float*)d_in[9];
    const float* c1_lb2 = (const float*)d_in[10];

    const float* c2_eW1 = (const float*)d_in[11];
    const float* c2_eb1 = (const float*)d_in[12];
    const float* c2_eW2 = (const float*)d_in[13];
    const float* c2_eb2 = (const float*)d_in[14];
    const float* c2_lW1 = (const float*)d_in[15];
    const float* c2_lb1 = (const float*)d_in[16];
    const float* c2_lW2 = (const float*)d_in[17];
    const float* c2_lb2 = (const float*)d_in[18];

    const float* c3_eW1 = (const float*)d_in[19];
    const float* c3_eb1 = (const float*)d_in[20];
    const float* c3_eW2 = (const float*)d_in[21];
    const float* c3_eb2 = (const float*)d_in[22];
    const float* c3_lW1 = (const float*)d_in[23];
    const float* c3_lb1 = (const float*)d_in[24];
    const float* c3_lW2 = (const float*)d_in[25];
    const float* c3_lb2 = (const float*)d_in[26];

    const float* fus_W1 = (const float*)d_in[27];
    const float* fus_b1 = (const float*)d_in[28];
    const float* fus_W2 = (const float*)d_in[29];
    const float* fus_b2 = (const float*)d_in[30];

    const int N = in_sizes[0] / 32;   // 25000
    const int E = in_sizes[1] / 2;    // 400000
    const int* srcI = eidx;
    const int* dstI = eidx + E;

    float* ws = (float*)d_ws;
    float* x1     = ws;
    float* x2     = x1 + (size_t)N * 128;
    float* x3     = x2 + (size_t)N * 128;
    float* agg    = x3 + (size_t)N * 128;
    float* w1p_c1 = agg + (size_t)N * 128;
    float* w1p_c2 = w1p_c1 + 104 * 128;
    float* w1p_c3 = w1p_c2 + 392 * 128;

    // pad edge-MLP W1 so K is a multiple of 4
    pad_w1_kernel<<<(104 * 128 + 255) / 256, 256, 0, stream>>>(c1_eW1, w1p_c1, 102, 104);
    pad_w1_kernel<<<(392 * 128 + 255) / 256, 256, 0, stream>>>(c2_eW1, w1p_c2, 390, 392);
    pad_w1_kernel<<<(392 * 128 + 255) / 256, 256, 0, stream>>>(c3_eW1, w1p_c3, 390, 392);

    const int eblocks = (E + 31) / 32;
    const int nblocks = (N + 31) / 32;
    const size_t aggBytes = (size_t)N * 128 * sizeof(float);

    // ---- layer 1 (FIN=32, no residual) ----
    hipMemsetAsync(agg, 0, aggBytes, stream);
    edge_conv_kernel<32, 102, 104><<<eblocks, 256, 0, stream>>>(
        x, srcI, dstI, ea, w1p_c1, c1_eb1, c1_eW2, c1_eb2, agg, E);
    node_kernel<32, false><<<nblocks, 256, 0, stream>>>(
        x, agg, c1_lW1, c1_lb1, c1_lW2, c1_lb2, x1, N);

    // ---- layer 2 (FIN=128, residual) ----
    hipMemsetAsync(agg, 0, aggBytes, stream);
    edge_conv_kernel<128, 390, 392><<<eblocks, 256, 0, stream>>>(
        x1, srcI, dstI, ea, w1p_c2, c2_eb1, c2_eW2, c2_eb2, agg, E);
    node_kernel<128, true><<<nblocks, 256, 0, stream>>>(
        x1, agg, c2_lW1, c2_lb1, c2_lW2, c2_lb2, x2, N);

    // ---- layer 3 (FIN=128, residual) ----
    hipMemsetAsync(agg, 0, aggBytes, stream);
    edge_conv_kernel<128, 390, 392><<<eblocks, 256, 0, stream>>>(
        x2, srcI, dstI, ea, w1p_c3, c3_eb1, c3_eW2, c3_eb2, agg, E);
    node_kernel<128, true><<<nblocks, 256, 0, stream>>>(
        x2, agg, c3_lW1, c3_lb1, c3_lW2, c3_lb2, x3, N);

    // ---- fusion ----
    fusion_kernel<<<nblocks, 256, 0, stream>>>(
        x1, x2, x3, fus_W1, fus_b1, fus_W2, fus_b2, (float*)d_out, N);
}

// Round 2
// 1171.347 us; speedup vs baseline: 2.4891x; 2.4891x over previous
//
#include <hip/hip_runtime.h>
#include <math.h>

#define DEV __device__ __forceinline__

typedef __attribute__((ext_vector_type(8))) short bf16x8;
typedef __attribute__((ext_vector_type(4))) float f32x4;

DEV short f2bf(float v) {
    union { float f; unsigned u; } c; c.f = v;
    unsigned r = c.u + 0x7fffu + ((c.u >> 16) & 1u);   // RNE
    return (short)(r >> 16);
}

// ---------------------------------------------------------------------------
// fp32 register-blocked GEMM tile (node / fusion path, unchanged from R1)
// ---------------------------------------------------------------------------
template<int KDIM, int LDIN, int WSTRIDE>
DEV void gemm_tile(const float* inLds, const float* __restrict__ W,
                   const float* __restrict__ b, int c0, int tid,
                   float (&acc)[4][4])
{
    const int tc  = tid & 31;
    const int tr  = tid >> 5;
    const int col = c0 + tc * 4;
#pragma unroll
    for (int jj = 0; jj < 4; ++jj) {
        const float bv = b[col + jj];
#pragma unroll
        for (int rr = 0; rr < 4; ++rr) acc[rr][jj] = bv;
    }
#pragma unroll 2
    for (int k = 0; k < KDIM; k += 4) {
        const float4 w0 = *(const float4*)&W[(size_t)(k + 0) * WSTRIDE + col];
        const float4 w1 = *(const float4*)&W[(size_t)(k + 1) * WSTRIDE + col];
        const float4 w2 = *(const float4*)&W[(size_t)(k + 2) * WSTRIDE + col];
        const float4 w3 = *(const float4*)&W[(size_t)(k + 3) * WSTRIDE + col];
#pragma unroll
        for (int rr = 0; rr < 4; ++rr) {
            const float4 f = *(const float4*)&inLds[(size_t)(tr * 4 + rr) * LDIN + k];
            acc[rr][0] = fmaf(f.x, w0.x, acc[rr][0]);
            acc[rr][1] = fmaf(f.x, w0.y, acc[rr][1]);
            acc[rr][2] = fmaf(f.x, w0.z, acc[rr][2]);
            acc[rr][3] = fmaf(f.x, w0.w, acc[rr][3]);
            acc[rr][0] = fmaf(f.y, w1.x, acc[rr][0]);
            acc[rr][1] = fmaf(f.y, w1.y, acc[rr][1]);
            acc[rr][2] = fmaf(f.y, w1.z, acc[rr][2]);
            acc[rr][3] = fmaf(f.y, w1.w, acc[rr][3]);
            acc[rr][0] = fmaf(f.z, w2.x, acc[rr][0]);
            acc[rr][1] = fmaf(f.z, w2.y, acc[rr][1]);
            acc[rr][2] = fmaf(f.z, w2.z, acc[rr][2]);
            acc[rr][3] = fmaf(f.z, w2.w, acc[rr][3]);
            acc[rr][0] = fmaf(f.w, w3.x, acc[rr][0]);
            acc[rr][1] = fmaf(f.w, w3.y, acc[rr][1]);
            acc[rr][2] = fmaf(f.w, w3.z, acc[rr][2]);
            acc[rr][3] = fmaf(f.w, w3.w, acc[rr][3]);
        }
    }
}

// ---------------------------------------------------------------------------
// Pack fp32 weight [EIN][128] -> bf16 MFMA-B-fragment order, K padded to KP.
// Layout: out[ ks*4096 + n*32 + kg*8 + i ] = W[ks*32+kg*8+i][n]  (shorts)
// ---------------------------------------------------------------------------
__global__ void pack_w_kernel(const float* __restrict__ W, short* __restrict__ out,
                              int EIN, int total)
{
    const int idx = blockIdx.x * 256 + threadIdx.x;
    if (idx >= total) return;
    const int ks = idx >> 12;
    const int w  = idx & 4095;
    const int n  = w >> 5;
    const int kg = (w >> 3) & 3;
    const int i  = w & 7;
    const int k  = ks * 32 + kg * 8 + i;
    const float v = (k < EIN) ? W[(size_t)k * 128 + n] : 0.0f;
    out[idx] = f2bf(v);
}

// ---------------------------------------------------------------------------
// MFMA GEMM over a 64-row LDS tile: per wave 16 rows x 128 cols.
// aLds rows are FSTR shorts; Wpk is packed as above; bias fp32[128].
// ---------------------------------------------------------------------------
template<int KP, int FSTR>
DEV void mfma_gemm(const short* aLds, const short* __restrict__ Wpk,
                   const float* __restrict__ b, int wave, int lane,
                   f32x4 (&acc)[8])
{
    const int l15 = lane & 15;
    const int lg  = lane >> 4;
#pragma unroll
    for (int f = 0; f < 8; ++f) {
        const float bv = b[f * 16 + l15];
        acc[f] = (f32x4){bv, bv, bv, bv};
    }
    const short* arow = aLds + (wave * 16 + l15) * FSTR + lg * 8;
    const short* wbase = Wpk + l15 * 32 + lg * 8;
#pragma unroll
    for (int ks = 0; ks < KP / 32; ++ks) {
        const bf16x8 av = *(const bf16x8*)(arow + ks * 32);
        const short* wp = wbase + ks * 4096;
#pragma unroll
        for (int f = 0; f < 8; ++f) {
            const bf16x8 bv = *(const bf16x8*)(wp + f * 512);
            acc[f] = __builtin_amdgcn_mfma_f32_16x16x32_bf16(av, bv, acc[f], 0, 0, 0);
        }
    }
}

// ---------------------------------------------------------------------------
// Edge conv (MFMA): 64 edges/block, 4 waves.
// feat = [xi, xj-xi, xj*xi, |d|, <xj,xi>, ea] (bf16, K padded to KP)
// m = relu(relu(feat@W1+b1)@W2+b2); atomicMax into agg[dst].
// ---------------------------------------------------------------------------
template<int FIN, int EIN, int KP, int FSTR>
__global__ __launch_bounds__(256)
void edge_conv_mfma(const float* __restrict__ x,
                    const int* __restrict__ srcIdx, const int* __restrict__ dstIdx,
                    const float* __restrict__ ea,
                    const short* __restrict__ W1pk, const float* __restrict__ b1,
                    const short* __restrict__ W2pk, const float* __restrict__ b2,
                    float* __restrict__ agg, int E)
{
    constexpr int H1STR = 136;
    __shared__ __align__(16) short feat[64 * FSTR];
    __shared__ __align__(16) short h1s[64 * H1STR];
    const int tid  = threadIdx.x;
    const int lane = tid & 63;
    const int wave = tid >> 6;
    const int e0   = blockIdx.x * 64;

    // ---- stage 1: gather + feature build (4 threads per edge) ----
    {
        const int r = tid >> 2;
        const int s = tid & 3;
        const int e = e0 + r;
        short* frow = &feat[r * FSTR];
        if (e < E) {
            const int si = srcIdx[e];
            const int di = dstIdx[e];
            const float4* xs = (const float4*)(x + (size_t)si * FIN);
            const float4* xd = (const float4*)(x + (size_t)di * FIN);
            float sd2 = 0.0f, sp = 0.0f;
#pragma unroll
            for (int d4 = s; d4 < FIN / 4; d4 += 4) {
                const float4 a = xs[d4];   // x_j (source)
                const float4 bv = xd[d4];  // x_i (target)
                const float dx = a.x - bv.x, dy = a.y - bv.y, dz = a.z - bv.z, dw = a.w - bv.w;
                const float px = a.x * bv.x, py = a.y * bv.y, pz = a.z * bv.z, pw = a.w * bv.w;
                sd2 += dx * dx + dy * dy + dz * dz + dw * dw;
                sp  += px + py + pz + pw;
                *(short4*)(frow + d4 * 4) =
                    make_short4(f2bf(bv.x), f2bf(bv.y), f2bf(bv.z), f2bf(bv.w));
                *(short4*)(frow + FIN + d4 * 4) =
                    make_short4(f2bf(dx), f2bf(dy), f2bf(dz), f2bf(dw));
                *(short4*)(frow + 2 * FIN + d4 * 4) =
                    make_short4(f2bf(px), f2bf(py), f2bf(pz), f2bf(pw));
            }
            sd2 += __shfl_xor(sd2, 1); sd2 += __shfl_xor(sd2, 2);
            sp  += __shfl_xor(sp, 1);  sp  += __shfl_xor(sp, 2);
            if (s == 0)
                *(short2*)(frow + 3 * FIN) = make_short2(f2bf(sqrtf(sd2)), f2bf(sp));
            if (s == 1) {
                const float4 av = *(const float4*)(ea + (size_t)e * 4);
                *(short2*)(frow + 3 * FIN + 2) = make_short2(f2bf(av.x), f2bf(av.y));
                *(short2*)(frow + 3 * FIN + 4) = make_short2(f2bf(av.z), f2bf(av.w));
            }
            for (int d = EIN + s; d < KP; d += 4) frow[d] = 0;
        } else {
            for (int d = s; d < KP; d += 4) frow[d] = 0;
        }
    }
    __syncthreads();

    const int l15 = lane & 15;
    const int lg  = lane >> 4;

    // ---- stage 2: h1 = relu(feat @ W1 + b1), pack bf16 into LDS ----
    {
        f32x4 acc[8];
        mfma_gemm<KP, FSTR>(feat, W1pk, b1, wave, lane, acc);
#pragma unroll
        for (int f = 0; f < 8; ++f)
#pragma unroll
            for (int i = 0; i < 4; ++i) {
                const float v = fmaxf(acc[f][i], 0.0f);
                const float o = __shfl_xor(v, 1);
                if (!(lane & 1)) {
                    const unsigned pk = ((unsigned)(unsigned short)f2bf(o) << 16) |
                                        (unsigned)(unsigned short)f2bf(v);
                    const int row = wave * 16 + lg * 4 + i;
                    *(unsigned*)&h1s[row * H1STR + f * 16 + l15] = pk;
                }
            }
    }
    __syncthreads();

    // ---- stage 3: m = relu(h1 @ W2 + b2); atomicMax into agg ----
    {
        f32x4 acc[8];
        mfma_gemm<128, H1STR>(h1s, W2pk, b2, wave, lane, acc);
        int dloc[4];
        bool ok[4];
#pragma unroll
        for (int i = 0; i < 4; ++i) {
            const int e = e0 + wave * 16 + lg * 4 + i;
            ok[i] = (e < E);
            dloc[i] = ok[i] ? dstIdx[e] : 0;
        }
#pragma unroll
        for (int f = 0; f < 8; ++f)
#pragma unroll
            for (int i = 0; i < 4; ++i) {
                if (ok[i]) {
                    const float v = fmaxf(acc[f][i], 0.0f);
                    atomicMax((int*)agg + (size_t)dloc[i] * 128 + f * 16 + l15,
                              __float_as_int(v));   // v>=0: int order == float order
                }
            }
    }
}

// ---------------------------------------------------------------------------
// Node MLP (fp32 VALU): y = relu(relu([x, agg]@W1+b1)@W2+b2) (+x if RES).
// ---------------------------------------------------------------------------
template<int FIN, bool RES>
__global__ __launch_bounds__(256)
void node_kernel(const float* __restrict__ xin, const float* __restrict__ agg,
                 const float* __restrict__ W1, const float* __restrict__ b1,
                 const float* __restrict__ W2, const float* __restrict__ b2,
                 float* __restrict__ out, int N)
{
    constexpr int K1 = FIN + 128;
    __shared__ __align__(16) float inb[32][K1];
    __shared__ __align__(16) float h1[32][128];
    const int tid = threadIdx.x;
    const int n0  = blockIdx.x * 32;
    {
        const int r = tid >> 3;
        const int s = tid & 7;
        const int n = n0 + r;
        if (n < N) {
            for (int d = s; d < FIN; d += 8) inb[r][d] = xin[(size_t)n * FIN + d];
            for (int d = s; d < 128; d += 8) inb[r][FIN + d] = agg[(size_t)n * 128 + d];
        } else {
            for (int d = s; d < K1; d += 8) inb[r][d] = 0.0f;
        }
    }
    __syncthreads();

    float acc[4][4];
    gemm_tile<K1, K1, 128>(&inb[0][0], W1, b1, 0, tid, acc);
    {
        const int tc = tid & 31, tr = tid >> 5;
#pragma unroll
        for (int rr = 0; rr < 4; ++rr) {
            float4 v;
            v.x = fmaxf(acc[rr][0], 0.0f);
            v.y = fmaxf(acc[rr][1], 0.0f);
            v.z = fmaxf(acc[rr][2], 0.0f);
            v.w = fmaxf(acc[rr][3], 0.0f);
            *(float4*)&h1[tr * 4 + rr][tc * 4] = v;
        }
    }
    __syncthreads();
    gemm_tile<128, 128, 128>(&h1[0][0], W2, b2, 0, tid, acc);
    {
        const int tc = tid & 31, tr = tid >> 5;
#pragma unroll
        for (int rr = 0; rr < 4; ++rr) {
            const int n = n0 + tr * 4 + rr;
            if (n < N) {
                const int col = tc * 4;
#pragma unroll
                for (int jj = 0; jj < 4; ++jj) {
                    float v = fmaxf(acc[rr][jj], 0.0f);
                    if (RES) v += xin[(size_t)n * 128 + col + jj];
                    out[(size_t)n * 128 + col + jj] = v;
                }
            }
        }
    }
}

// ---------------------------------------------------------------------------
// Fusion MLP (fp32 VALU): out = relu(relu([x1,x2,x3]@W1+b1)@W2+b2).
// ---------------------------------------------------------------------------
__global__ __launch_bounds__(256)
void fusion_kernel(const float* __restrict__ x1, const float* __restrict__ x2,
                   const float* __restrict__ x3,
                   const float* __restrict__ W1, const float* __restrict__ b1,
                   const float* __restrict__ W2, const float* __restrict__ b2,
                   float* __restrict__ out, int N)
{
    __shared__ __align__(16) float inb[32][384];
    __shared__ __align__(16) float h1[32][256];
    const int tid = threadIdx.x;
    const int n0  = blockIdx.x * 32;
    {
        const int r = tid >> 3;
        const int s = tid & 7;
        const int n = n0 + r;
        if (n < N) {
            for (int d = s; d < 128; d += 8) {
                inb[r][d]       = x1[(size_t)n * 128 + d];
                inb[r][128 + d] = x2[(size_t)n * 128 + d];
                inb[r][256 + d] = x3[(size_t)n * 128 + d];
            }
        } else {
            for (int d = s; d < 384; d += 8) inb[r][d] = 0.0f;
        }
    }
    __syncthreads();

    float acc[4][4];
#pragma unroll
    for (int c0 = 0; c0 < 256; c0 += 128) {
        gemm_tile<384, 384, 256>(&inb[0][0], W1, b1, c0, tid, acc);
        const int tc = tid & 31, tr = tid >> 5;
#pragma unroll
        for (int rr = 0; rr < 4; ++rr) {
            float4 v;
            v.x = fmaxf(acc[rr][0], 0.0f);
            v.y = fmaxf(acc[rr][1], 0.0f);
            v.z = fmaxf(acc[rr][2], 0.0f);
            v.w = fmaxf(acc[rr][3], 0.0f);
            *(float4*)&h1[tr * 4 + rr][c0 + tc * 4] = v;
        }
    }
    __syncthreads();
    gemm_tile<256, 256, 128>(&h1[0][0], W2, b2, 0, tid, acc);
    {
        const int tc = tid & 31, tr = tid >> 5;
#pragma unroll
        for (int rr = 0; rr < 4; ++rr) {
            const int n = n0 + tr * 4 + rr;
            if (n < N) {
#pragma unroll
                for (int jj = 0; jj < 4; ++jj)
                    out[(size_t)n * 128 + tc * 4 + jj] = fmaxf(acc[rr][jj], 0.0f);
            }
        }
    }
}

// ---------------------------------------------------------------------------
extern "C" void kernel_launch(void* const* d_in, const int* in_sizes, int n_in,
                              void* d_out, int out_size, void* d_ws, size_t ws_size,
                              hipStream_t stream)
{
    const float* x    = (const float*)d_in[0];
    const int*   eidx = (const int*)d_in[1];
    const float* ea   = (const float*)d_in[2];

    const float* c1_eW1 = (const float*)d_in[3];
    const float* c1_eb1 = (const float*)d_in[4];
    const float* c1_eW2 = (const float*)d_in[5];
    const float* c1_eb2 = (const float*)d_in[6];
    const float* c1_lW1 = (const float*)d_in[7];
    const float* c1_lb1 = (const float*)d_in[8];
    const float* c1_lW2 = (const float*)d_in[9];
    const float* c1_lb2 = (const float*)d_in[10];

    const float* c2_eW1 = (const float*)d_in[11];
    const float* c2_eb1 = (const float*)d_in[12];
    const float* c2_eW2 = (const float*)d_in[13];
    const float* c2_eb2 = (const float*)d_in[14];
    const float* c2_lW1 = (const float*)d_in[15];
    const float* c2_lb1 = (const float*)d_in[16];
    const float* c2_lW2 = (const float*)d_in[17];
    const float* c2_lb2 = (const float*)d_in[18];

    const float* c3_eW1 = (const float*)d_in[19];
    const float* c3_eb1 = (const float*)d_in[20];
    const float* c3_eW2 = (const float*)d_in[21];
    const float* c3_eb2 = (const float*)d_in[22];
    const float* c3_lW1 = (const float*)d_in[23];
    const float* c3_lb1 = (const float*)d_in[24];
    const float* c3_lW2 = (const float*)d_in[25];
    const float* c3_lb2 = (const float*)d_in[26];

    const float* fus_W1 = (const float*)d_in[27];
    const float* fus_b1 = (const float*)d_in[28];
    const float* fus_W2 = (const float*)d_in[29];
    const float* fus_b2 = (const float*)d_in[30];

    const int N = in_sizes[0] / 32;   // 25000
    const int E = in_sizes[1] / 2;    // 400000
    const int* srcI = eidx;
    const int* dstI = eidx + E;

    float* ws = (float*)d_ws;
    float* x1  = ws;
    float* x2  = x1 + (size_t)N * 128;
    float* x3  = x2 + (size_t)N * 128;
    float* agg = x3 + (size_t)N * 128;
    short* w1pk_c1 = (short*)(agg + (size_t)N * 128);      // 128*128
    short* w2pk_c1 = w1pk_c1 + 128 * 128;                  // 128*128
    short* w1pk_c2 = w2pk_c1 + 128 * 128;                  // 416*128
    short* w2pk_c2 = w1pk_c2 + 416 * 128;                  // 128*128
    short* w1pk_c3 = w2pk_c2 + 128 * 128;                  // 416*128
    short* w2pk_c3 = w1pk_c3 + 416 * 128;                  // 128*128

    // ---- pack weights to bf16 MFMA fragment layout ----
    pack_w_kernel<<<(128 * 128 + 255) / 256, 256, 0, stream>>>(c1_eW1, w1pk_c1, 102, 128 * 128);
    pack_w_kernel<<<(128 * 128 + 255) / 256, 256, 0, stream>>>(c1_eW2, w2pk_c1, 128, 128 * 128);
    pack_w_kernel<<<(416 * 128 + 255) / 256, 256, 0, stream>>>(c2_eW1, w1pk_c2, 390, 416 * 128);
    pack_w_kernel<<<(128 * 128 + 255) / 256, 256, 0, stream>>>(c2_eW2, w2pk_c2, 128, 128 * 128);
    pack_w_kernel<<<(416 * 128 + 255) / 256, 256, 0, stream>>>(c3_eW1, w1pk_c3, 390, 416 * 128);
    pack_w_kernel<<<(128 * 128 + 255) / 256, 256, 0, stream>>>(c3_eW2, w2pk_c3, 128, 128 * 128);

    const int eblocks = (E + 63) / 64;
    const int nblocks = (N + 31) / 32;
    const size_t aggBytes = (size_t)N * 128 * sizeof(float);

    // ---- layer 1 (FIN=32, EIN=102, KP=128) ----
    hipMemsetAsync(agg, 0, aggBytes, stream);
    edge_conv_mfma<32, 102, 128, 136><<<eblocks, 256, 0, stream>>>(
        x, srcI, dstI, ea, w1pk_c1, c1_eb1, w2pk_c1, c1_eb2, agg, E);
    node_kernel<32, false><<<nblocks, 256, 0, stream>>>(
        x, agg, c1_lW1, c1_lb1, c1_lW2, c1_lb2, x1, N);

    // ---- layer 2 (FIN=128, EIN=390, KP=416, residual) ----
    hipMemsetAsync(agg, 0, aggBytes, stream);
    edge_conv_mfma<128, 390, 416, 424><<<eblocks, 256, 0, stream>>>(
        x1, srcI, dstI, ea, w1pk_c2, c2_eb1, w2pk_c2, c2_eb2, agg, E);
    node_kernel<128, true><<<nblocks, 256, 0, stream>>>(
        x1, agg, c2_lW1, c2_lb1, c2_lW2, c2_lb2, x2, N);

    // ---- layer 3 (FIN=128, EIN=390, KP=416, residual) ----
    hipMemsetAsync(agg, 0, aggBytes, stream);
    edge_conv_mfma<128, 390, 416, 424><<<eblocks, 256, 0, stream>>>(
        x2, srcI, dstI, ea, w1pk_c3, c3_eb1, w2pk_c3, c3_eb2, agg, E);
    node_kernel<128, true><<<nblocks, 256, 0, stream>>>(
        x2, agg, c3_lW1, c3_lb1, c3_lW2, c3_lb2, x3, N);

    // ---- fusion ----
    fusion_kernel<<<nblocks, 256, 0, stream>>>(
        x1, x2, x3, fus_W1, fus_b1, fus_W2, fus_b2, (float*)d_out, N);
}

// Round 3
// 945.362 us; speedup vs baseline: 3.0841x; 1.2390x over previous
//
#include <hip/hip_runtime.h>
#include <math.h>

#define DEV __device__ __forceinline__

typedef __attribute__((ext_vector_type(8))) short bf16x8;
typedef __attribute__((ext_vector_type(4))) float f32x4;

DEV short f2bf(float v) {
    union { float f; unsigned u; } c; c.f = v;
    unsigned r = c.u + 0x7fffu + ((c.u >> 16) & 1u);   // RNE
    return (short)(r >> 16);
}

// ===========================================================================
// Weight packing: W [KIN][NOUT] f32 -> bf16 MFMA-B fragments, K padded to KP.
// layout: out[ks*(NOUT*32) + n*32 + kg*8 + i] = W[ks*32+kg*8+i][n]
// ===========================================================================
#define NPACK 14
struct PackJobs {
    const float* W[NPACK];
    short* out[NPACK];
    int KIN[NPACK];
    int NOUT[NPACK];
    int end[NPACK];   // cumulative element counts
};

__global__ __launch_bounds__(256)
void pack_all(PackJobs j, int total)
{
    const int idx = blockIdx.x * 256 + threadIdx.x;
    if (idx >= total) return;
    int job = 0;
    while (idx >= j.end[job]) ++job;
    const int base = job ? j.end[job - 1] : 0;
    const int w = idx - base;
    const int nout = j.NOUT[job];
    const int per_ks = nout * 32;
    const int ks = w / per_ks;
    const int r  = w - ks * per_ks;
    const int n  = r >> 5;
    const int kg = (r >> 3) & 3;
    const int i  = r & 7;
    const int k  = ks * 32 + kg * 8 + i;
    j.out[job][w] = (k < j.KIN[job]) ? f2bf(j.W[job][(size_t)k * nout + n]) : (short)0;
}

// ===========================================================================
// Sorting by dst: histogram -> in-place exclusive scan -> scatter
// ===========================================================================
__global__ __launch_bounds__(256)
void hist_kernel(const int* __restrict__ dst, int* __restrict__ cnt, int E)
{
    const int e = blockIdx.x * 256 + threadIdx.x;
    if (e < E) atomicAdd(&cnt[dst[e]], 1);
}

__global__ __launch_bounds__(1024)
void scan_kernel(int* __restrict__ cnt, int NB)
{
    __shared__ int part[1024];
    const int t = threadIdx.x;
    const int CH = (NB + 1023) >> 10;
    const int base = t * CH;
    int s = 0;
    for (int k = 0; k < CH; ++k) { const int i = base + k; if (i < NB) s += cnt[i]; }
    part[t] = s;
    __syncthreads();
    for (int off = 1; off < 1024; off <<= 1) {
        const int add = (t >= off) ? part[t - off] : 0;
        __syncthreads();
        part[t] += add;
        __syncthreads();
    }
    int run = part[t] - s;           // exclusive prefix for this chunk
    for (int k = 0; k < CH; ++k) {
        const int i = base + k;
        if (i < NB) { const int c = cnt[i]; cnt[i] = run; run += c; }
    }
}

__global__ __launch_bounds__(256)
void scatter_kernel(const int* __restrict__ src, const int* __restrict__ dst,
                    const float* __restrict__ ea, int* __restrict__ cursor,
                    int* __restrict__ sSrc, int* __restrict__ sDst,
                    float* __restrict__ eaS, int E)
{
    const int e = blockIdx.x * 256 + threadIdx.x;
    if (e >= E) return;
    const int d = dst[e];
    const int p = atomicAdd(&cursor[d], 1);
    sSrc[p] = src[e];
    sDst[p] = d;
    ((float4*)eaS)[p] = ((const float4*)ea)[e];
}

// ===========================================================================
// MFMA GEMM over an LDS row-tile: one wave computes 16 rows x 128 cols.
// aLds rows are FSTR shorts; Wpk packed as above; b fp32 bias.
// ===========================================================================
template<int KP, int FSTR, int NOUT>
DEV void mfma_gemm(const short* aLds, const short* __restrict__ Wpk,
                   const float* __restrict__ b, int row0, int c0, int lane,
                   f32x4 (&acc)[8])
{
    const int l15 = lane & 15;
    const int lg  = lane >> 4;
#pragma unroll
    for (int f = 0; f < 8; ++f) {
        const float bv = b[c0 + f * 16 + l15];
        acc[f] = (f32x4){bv, bv, bv, bv};
    }
    const short* arow  = aLds + (row0 + l15) * FSTR + lg * 8;
    const short* wbase = Wpk + (size_t)(c0 + l15) * 32 + lg * 8;
#pragma unroll
    for (int ks = 0; ks < KP / 32; ++ks) {
        const bf16x8 av = *(const bf16x8*)(arow + ks * 32);
        const short* wp = wbase + (size_t)ks * NOUT * 32;
#pragma unroll
        for (int f = 0; f < 8; ++f) {
            const bf16x8 bv = *(const bf16x8*)(wp + f * 512);
            acc[f] = __builtin_amdgcn_mfma_f32_16x16x32_bf16(av, bv, acc[f], 0, 0, 0);
        }
    }
}

// relu(acc) -> packed bf16 rows in LDS (cols c0..c0+127)
template<int H1STR>
DEV void pack_h1(const f32x4 (&acc)[8], short* h1s, int row0, int c0, int lane)
{
    const int l15 = lane & 15;
    const int lg  = lane >> 4;
#pragma unroll
    for (int f = 0; f < 8; ++f)
#pragma unroll
        for (int i = 0; i < 4; ++i) {
            const float v = fmaxf(acc[f][i], 0.0f);
            const float o = __shfl_xor(v, 1);
            if (!(lane & 1)) {
                const unsigned pk = ((unsigned)(unsigned short)f2bf(o) << 16) |
                                    (unsigned)(unsigned short)f2bf(v);
                const int row = row0 + lg * 4 + i;
                *(unsigned*)&h1s[row * H1STR + c0 + f * 16 + l15] = pk;
            }
        }
}

// ===========================================================================
// Edge conv (sorted edges): 64 edges/block, 4 waves.
// feat=[xi, xj-xi, xj*xi, |d|, <xj,xi>, ea] -> m=relu(relu(feat@W1+b1)@W2+b2)
// -> block-local run-max over sorted dst -> atomicMax per run.
// ===========================================================================
template<int FIN, int EIN, int KP, int FSTR>
__global__ __launch_bounds__(256)
void edge_conv_mfma(const float* __restrict__ x,
                    const int* __restrict__ sSrc, const int* __restrict__ sDst,
                    const float* __restrict__ eaS,
                    const short* __restrict__ W1pk, const float* __restrict__ b1,
                    const short* __restrict__ W2pk, const float* __restrict__ b2,
                    float* __restrict__ agg, int E)
{
    constexpr int H1STR = 136;
    __shared__ __align__(16) short sh[64 * FSTR + 64 * H1STR];
    __shared__ int dstv[64];
    short* feat = sh;
    short* h1s  = sh + 64 * FSTR;
    const int tid  = threadIdx.x;
    const int lane = tid & 63;
    const int wave = tid >> 6;
    const int e0   = blockIdx.x * 64;

    // ---- stage 1: gather + feature build (4 threads per edge) ----
    {
        const int r = tid >> 2;
        const int s = tid & 3;
        const int e = e0 + r;
        short* frow = &feat[r * FSTR];
        if (e < E) {
            const int si = sSrc[e];
            const int di = sDst[e];
            if (s == 0) dstv[r] = di;
            const float4* xs = (const float4*)(x + (size_t)si * FIN);
            const float4* xd = (const float4*)(x + (size_t)di * FIN);
            float sd2 = 0.0f, sp = 0.0f;
#pragma unroll
            for (int d4 = s; d4 < FIN / 4; d4 += 4) {
                const float4 a  = xs[d4];   // x_j (source)
                const float4 bv = xd[d4];   // x_i (target)
                const float dx = a.x - bv.x, dy = a.y - bv.y, dz = a.z - bv.z, dw = a.w - bv.w;
                const float px = a.x * bv.x, py = a.y * bv.y, pz = a.z * bv.z, pw = a.w * bv.w;
                sd2 += dx * dx + dy * dy + dz * dz + dw * dw;
                sp  += px + py + pz + pw;
                *(short4*)(frow + d4 * 4) =
                    make_short4(f2bf(bv.x), f2bf(bv.y), f2bf(bv.z), f2bf(bv.w));
                *(short4*)(frow + FIN + d4 * 4) =
                    make_short4(f2bf(dx), f2bf(dy), f2bf(dz), f2bf(dw));
                *(short4*)(frow + 2 * FIN + d4 * 4) =
                    make_short4(f2bf(px), f2bf(py), f2bf(pz), f2bf(pw));
            }
            sd2 += __shfl_xor(sd2, 1); sd2 += __shfl_xor(sd2, 2);
            sp  += __shfl_xor(sp, 1);  sp  += __shfl_xor(sp, 2);
            if (s == 0)
                *(short2*)(frow + 3 * FIN) = make_short2(f2bf(sqrtf(sd2)), f2bf(sp));
            if (s == 1) {
                const float4 av = *(const float4*)(eaS + (size_t)e * 4);
                *(short2*)(frow + 3 * FIN + 2) = make_short2(f2bf(av.x), f2bf(av.y));
                *(short2*)(frow + 3 * FIN + 4) = make_short2(f2bf(av.z), f2bf(av.w));
            }
            for (int d = EIN + s; d < KP; d += 4) frow[d] = 0;
        } else {
            if (s == 0) dstv[r] = -1;
            for (int d = s; d < KP; d += 4) frow[d] = 0;
        }
    }
    __syncthreads();

    // ---- stage 2: h1 = relu(feat @ W1 + b1) ----
    f32x4 acc[8];
    mfma_gemm<KP, FSTR, 128>(feat, W1pk, b1, wave * 16, 0, lane, acc);
    pack_h1<H1STR>(acc, h1s, wave * 16, 0, lane);
    __syncthreads();

    // ---- stage 3: m = relu(h1 @ W2 + b2) ----
    mfma_gemm<128, H1STR, 128>(h1s, W2pk, b2, wave * 16, 0, lane, acc);
    __syncthreads();                      // all h1s reads done -> reuse sh as mbuf
    float* mbuf = (float*)sh;             // [64][132] f32
    {
        const int l15 = lane & 15;
        const int lg  = lane >> 4;
#pragma unroll
        for (int f = 0; f < 8; ++f)
#pragma unroll
            for (int i = 0; i < 4; ++i) {
                const int row = wave * 16 + lg * 4 + i;
                mbuf[row * 132 + f * 16 + l15] = fmaxf(acc[f][i], 0.0f);
            }
    }
    __syncthreads();

    // ---- stage 4: run-max over sorted dst, one atomic per (run, col) ----
    {
        const int c  = tid >> 1;          // 0..127
        const int rh = tid & 1;           // row half
        int cur = -1;
        float mx = 0.0f;
#pragma unroll 4
        for (int i2 = 0; i2 < 32; ++i2) {
            const int row = rh * 32 + i2;
            const int d = dstv[row];
            const float v = mbuf[row * 132 + c];
            if (d != cur) {
                if (cur >= 0)
                    atomicMax((int*)agg + (size_t)cur * 128 + c, __float_as_int(mx));
                cur = d;
                mx = v;
            } else {
                mx = fmaxf(mx, v);
            }
        }
        if (cur >= 0)
            atomicMax((int*)agg + (size_t)cur * 128 + c, __float_as_int(mx));
    }
}

// ===========================================================================
// Node MLP (MFMA): y = relu(relu([x,agg]@W1+b1)@W2+b2) (+x if RES).
// 64 nodes/block, 4 waves.
// ===========================================================================
template<int FIN, int KP, int FSTR, bool RES>
__global__ __launch_bounds__(256)
void node_mfma(const float* __restrict__ xin, const float* __restrict__ agg,
               const short* __restrict__ W1pk, const float* __restrict__ b1,
               const short* __restrict__ W2pk, const float* __restrict__ b2,
               float* __restrict__ out, int N)
{
    constexpr int H1STR = 136;
    __shared__ __align__(16) short sh[64 * FSTR + 64 * H1STR];
    short* feat = sh;
    short* h1s  = sh + 64 * FSTR;
    const int tid  = threadIdx.x;
    const int lane = tid & 63;
    const int wave = tid >> 6;
    const int n0   = blockIdx.x * 64;

    {
        const int r = tid >> 2;
        const int s = tid & 3;
        const int n = n0 + r;
        short* frow = &feat[r * FSTR];
        if (n < N) {
            const float4* xr = (const float4*)(xin + (size_t)n * FIN);
            const float4* ar = (const float4*)(agg + (size_t)n * 128);
#pragma unroll
            for (int d4 = s; d4 < FIN / 4; d4 += 4) {
                const float4 v = xr[d4];
                *(short4*)(frow + d4 * 4) = make_short4(f2bf(v.x), f2bf(v.y), f2bf(v.z), f2bf(v.w));
            }
#pragma unroll
            for (int d4 = s; d4 < 32; d4 += 4) {
                const float4 v = ar[d4];
                *(short4*)(frow + FIN + d4 * 4) = make_short4(f2bf(v.x), f2bf(v.y), f2bf(v.z), f2bf(v.w));
            }
        } else {
            for (int d = s; d < KP; d += 4) frow[d] = 0;
        }
    }
    __syncthreads();

    f32x4 acc[8];
    mfma_gemm<KP, FSTR, 128>(feat, W1pk, b1, wave * 16, 0, lane, acc);
    pack_h1<H1STR>(acc, h1s, wave * 16, 0, lane);
    __syncthreads();
    mfma_gemm<128, H1STR, 128>(h1s, W2pk, b2, wave * 16, 0, lane, acc);
    {
        const int l15 = lane & 15;
        const int lg  = lane >> 4;
#pragma unroll
        for (int f = 0; f < 8; ++f)
#pragma unroll
            for (int i = 0; i < 4; ++i) {
                const int n = n0 + wave * 16 + lg * 4 + i;
                if (n < N) {
                    const int c = f * 16 + l15;
                    float v = fmaxf(acc[f][i], 0.0f);
                    if (RES) v += xin[(size_t)n * 128 + c];
                    out[(size_t)n * 128 + c] = v;
                }
            }
    }
}

// ===========================================================================
// Fusion MLP (MFMA): out = relu(relu([x1,x2,x3]@W1+b1)@W2+b2).
// 32 nodes/block, 2 waves. W1: 384->256, W2: 256->128.
// ===========================================================================
__global__ __launch_bounds__(128)
void fusion_mfma(const float* __restrict__ x1, const float* __restrict__ x2,
                 const float* __restrict__ x3,
                 const short* __restrict__ W1pk, const float* __restrict__ b1,
                 const short* __restrict__ W2pk, const float* __restrict__ b2,
                 float* __restrict__ out, int N)
{
    constexpr int FSTR = 392;     // 384 + 8
    constexpr int H1STR = 264;    // 256 + 8
    __shared__ __align__(16) short sh[32 * FSTR + 32 * H1STR];
    short* feat = sh;
    short* h1s  = sh + 32 * FSTR;
    const int tid  = threadIdx.x;
    const int lane = tid & 63;
    const int wave = tid >> 6;
    const int n0   = blockIdx.x * 32;

    {
        const int r = tid >> 2;
        const int s = tid & 3;
        const int n = n0 + r;
        short* frow = &feat[r * FSTR];
        if (n < N) {
            const float4* a1 = (const float4*)(x1 + (size_t)n * 128);
            const float4* a2 = (const float4*)(x2 + (size_t)n * 128);
            const float4* a3 = (const float4*)(x3 + (size_t)n * 128);
#pragma unroll
            for (int d4 = s; d4 < 32; d4 += 4) {
                const float4 v1 = a1[d4], v2 = a2[d4], v3 = a3[d4];
                *(short4*)(frow + d4 * 4)       = make_short4(f2bf(v1.x), f2bf(v1.y), f2bf(v1.z), f2bf(v1.w));
                *(short4*)(frow + 128 + d4 * 4) = make_short4(f2bf(v2.x), f2bf(v2.y), f2bf(v2.z), f2bf(v2.w));
                *(short4*)(frow + 256 + d4 * 4) = make_short4(f2bf(v3.x), f2bf(v3.y), f2bf(v3.z), f2bf(v3.w));
            }
        } else {
            for (int d = s; d < 384; d += 4) frow[d] = 0;
        }
    }
    __syncthreads();

    f32x4 acc[8];
#pragma unroll
    for (int c0 = 0; c0 < 256; c0 += 128) {
        mfma_gemm<384, FSTR, 256>(feat, W1pk, b1, wave * 16, c0, lane, acc);
        pack_h1<H1STR>(acc, h1s, wave * 16, c0, lane);
    }
    __syncthreads();
    mfma_gemm<256, H1STR, 128>(h1s, W2pk, b2, wave * 16, 0, lane, acc);
    {
        const int l15 = lane & 15;
        const int lg  = lane >> 4;
#pragma unroll
        for (int f = 0; f < 8; ++f)
#pragma unroll
            for (int i = 0; i < 4; ++i) {
                const int n = n0 + wave * 16 + lg * 4 + i;
                if (n < N)
                    out[(size_t)n * 128 + f * 16 + l15] = fmaxf(acc[f][i], 0.0f);
            }
    }
}

// ===========================================================================
extern "C" void kernel_launch(void* const* d_in, const int* in_sizes, int n_in,
                              void* d_out, int out_size, void* d_ws, size_t ws_size,
                              hipStream_t stream)
{
    const float* x    = (const float*)d_in[0];
    const int*   eidx = (const int*)d_in[1];
    const float* ea   = (const float*)d_in[2];

    const float* c1_eW1 = (const float*)d_in[3];
    const float* c1_eb1 = (const float*)d_in[4];
    const float* c1_eW2 = (const float*)d_in[5];
    const float* c1_eb2 = (const float*)d_in[6];
    const float* c1_lW1 = (const float*)d_in[7];
    const float* c1_lb1 = (const float*)d_in[8];
    const float* c1_lW2 = (const float*)d_in[9];
    const float* c1_lb2 = (const float*)d_in[10];

    const float* c2_eW1 = (const float*)d_in[11];
    const float* c2_eb1 = (const float*)d_in[12];
    const float* c2_eW2 = (const float*)d_in[13];
    const float* c2_eb2 = (const float*)d_in[14];
    const float* c2_lW1 = (const float*)d_in[15];
    const float* c2_lb1 = (const float*)d_in[16];
    const float* c2_lW2 = (const float*)d_in[17];
    const float* c2_lb2 = (const float*)d_in[18];

    const float* c3_eW1 = (const float*)d_in[19];
    const float* c3_eb1 = (const float*)d_in[20];
    const float* c3_eW2 = (const float*)d_in[21];
    const float* c3_eb2 = (const float*)d_in[22];
    const float* c3_lW1 = (const float*)d_in[23];
    const float* c3_lb1 = (const float*)d_in[24];
    const float* c3_lW2 = (const float*)d_in[25];
    const float* c3_lb2 = (const float*)d_in[26];

    const float* fus_W1 = (const float*)d_in[27];
    const float* fus_b1 = (const float*)d_in[28];
    const float* fus_W2 = (const float*)d_in[29];
    const float* fus_b2 = (const float*)d_in[30];

    const int N = in_sizes[0] / 32;   // 25000
    const int E = in_sizes[1] / 2;    // 400000
    const int* srcI = eidx;
    const int* dstI = eidx + E;

    const size_t NP = (size_t)N * 128;
    float* ws  = (float*)d_ws;
    float* x1  = ws;
    float* x2  = x1 + NP;
    float* x3  = x2 + NP;
    float* agg = x3 + NP;
    float* eaS = agg + NP;
    int* cursor = (int*)(eaS + (size_t)E * 4);
    int* sSrc   = cursor + 25024;
    int* sDst   = sSrc + E;
    short* wpk  = (short*)(sDst + E);

    // packed-weight sub-buffers (cumulative offsets)
    short* w1e1 = wpk + 0;       // c1_eW1 KP=128         16384
    short* w2e1 = wpk + 16384;   // c1_eW2 KP=128         16384
    short* w1e2 = wpk + 32768;   // c2_eW1 KP=416         53248
    short* w2e2 = wpk + 86016;   // c2_eW2                16384
    short* w1e3 = wpk + 102400;  // c3_eW1                53248
    short* w2e3 = wpk + 155648;  // c3_eW2                16384
    short* n1W1 = wpk + 172032;  // c1_lW1 KP=160         20480
    short* n1W2 = wpk + 192512;  // c1_lW2                16384
    short* n2W1 = wpk + 208896;  // c2_lW1 KP=256         32768
    short* n2W2 = wpk + 241664;  // c2_lW2                16384
    short* n3W1 = wpk + 258048;  // c3_lW1                32768
    short* n3W2 = wpk + 290816;  // c3_lW2                16384
    short* fW1  = wpk + 307200;  // fus_W1 KP=384 N=256   98304
    short* fW2  = wpk + 405504;  // fus_W2 KP=256         32768
    const int packTotal = 438272;

    PackJobs pj;
    const float* pw[NPACK] = {c1_eW1, c1_eW2, c2_eW1, c2_eW2, c3_eW1, c3_eW2,
                              c1_lW1, c1_lW2, c2_lW1, c2_lW2, c3_lW1, c3_lW2,
                              fus_W1, fus_W2};
    short* po[NPACK] = {w1e1, w2e1, w1e2, w2e2, w1e3, w2e3,
                        n1W1, n1W2, n2W1, n2W2, n3W1, n3W2, fW1, fW2};
    const int pk_kin[NPACK]  = {102,128,390,128,390,128, 160,128,256,128,256,128, 384,256};
    const int pk_nout[NPACK] = {128,128,128,128,128,128, 128,128,128,128,128,128, 256,128};
    const int pk_end[NPACK]  = {16384,32768,86016,102400,155648,172032,
                                192512,208896,241664,258048,290816,307200,405504,438272};
    for (int i = 0; i < NPACK; ++i) {
        pj.W[i] = pw[i]; pj.out[i] = po[i];
        pj.KIN[i] = pk_kin[i]; pj.NOUT[i] = pk_nout[i]; pj.end[i] = pk_end[i];
    }
    pack_all<<<(packTotal + 255) / 256, 256, 0, stream>>>(pj, packTotal);

    // ---- sort edges by dst ----
    const int eblk = (E + 255) / 256;
    hipMemsetAsync(cursor, 0, 25024 * sizeof(int), stream);
    hist_kernel<<<eblk, 256, 0, stream>>>(dstI, cursor, E);
    scan_kernel<<<1, 1024, 0, stream>>>(cursor, N);
    scatter_kernel<<<eblk, 256, 0, stream>>>(srcI, dstI, ea, cursor, sSrc, sDst, eaS, E);

    const int eblocks = (E + 63) / 64;
    const int nblocks = (N + 63) / 64;
    const int fblocks = (N + 31) / 32;
    const size_t aggBytes = NP * sizeof(float);

    // ---- layer 1 (FIN=32, EIN=102, KP=128) ----
    hipMemsetAsync(agg, 0, aggBytes, stream);
    edge_conv_mfma<32, 102, 128, 136><<<eblocks, 256, 0, stream>>>(
        x, sSrc, sDst, eaS, w1e1, c1_eb1, w2e1, c1_eb2, agg, E);
    node_mfma<32, 160, 168, false><<<nblocks, 256, 0, stream>>>(
        x, agg, n1W1, c1_lb1, n1W2, c1_lb2, x1, N);

    // ---- layer 2 (FIN=128, EIN=390, KP=416, residual) ----
    hipMemsetAsync(agg, 0, aggBytes, stream);
    edge_conv_mfma<128, 390, 416, 424><<<eblocks, 256, 0, stream>>>(
        x1, sSrc, sDst, eaS, w1e2, c2_eb1, w2e2, c2_eb2, agg, E);
    node_mfma<128, 256, 264, true><<<nblocks, 256, 0, stream>>>(
        x1, agg, n2W1, c2_lb1, n2W2, c2_lb2, x2, N);

    // ---- layer 3 (FIN=128, EIN=390, KP=416, residual) ----
    hipMemsetAsync(agg, 0, aggBytes, stream);
    edge_conv_mfma<128, 390, 416, 424><<<eblocks, 256, 0, stream>>>(
        x2, sSrc, sDst, eaS, w1e3, c3_eb1, w2e3, c3_eb2, agg, E);
    node_mfma<128, 256, 264, true><<<nblocks, 256, 0, stream>>>(
        x2, agg, n3W1, c3_lb1, n3W2, c3_lb2, x3, N);

    // ---- fusion ----
    fusion_mfma<<<fblocks, 128, 0, stream>>>(
        x1, x2, x3, fW1, fus_b1, fW2, fus_b2, (float*)d_out, N);
}

// Round 4
// 799.921 us; speedup vs baseline: 3.6448x; 1.1818x over previous
//
#include <hip/hip_runtime.h>
#include <math.h>

#define DEV __device__ __forceinline__

typedef __attribute__((ext_vector_type(8))) short bf16x8;
typedef __attribute__((ext_vector_type(4))) float f32x4;

DEV short f2bf(float v) {
    union { float f; unsigned u; } c; c.f = v;
    unsigned r = c.u + 0x7fffu + ((c.u >> 16) & 1u);   // RNE
    return (short)(r >> 16);
}
DEV float bf2f(short s) {
    return __uint_as_float(((unsigned)(unsigned short)s) << 16);
}

// ===========================================================================
// Weight packing: W [KIN][NOUT] f32 (optionally minus Wsub) -> bf16 MFMA-B
// fragments. layout: out[ks*(NOUT*32) + n*32 + kg*8 + i] = W[ks*32+kg*8+i][n]
// All jobs write into one contiguous output buffer.
// ===========================================================================
#define NPACK 20
struct PackJobs {
    const float* W[NPACK];
    const float* Wsub[NPACK];
    int KIN[NPACK];
    int NOUT[NPACK];
    int end[NPACK];   // cumulative element counts
};

__global__ __launch_bounds__(256)
void pack_all(PackJobs j, short* __restrict__ out, int total)
{
    const int idx = blockIdx.x * 256 + threadIdx.x;
    if (idx >= total) return;
    int job = 0;
    while (idx >= j.end[job]) ++job;
    const int base = job ? j.end[job - 1] : 0;
    const int w = idx - base;
    const int nout = j.NOUT[job];
    const int per_ks = nout * 32;
    const int ks = w / per_ks;
    const int r  = w - ks * per_ks;
    const int n  = r >> 5;
    const int kg = (r >> 3) & 3;
    const int i  = r & 7;
    const int k  = ks * 32 + kg * 8 + i;
    float val = 0.0f;
    if (k < j.KIN[job]) {
        val = j.W[job][(size_t)k * nout + n];
        if (j.Wsub[job]) val -= j.Wsub[job][(size_t)k * nout + n];
    }
    out[idx] = f2bf(val);
}

// ===========================================================================
// Sorting by dst: histogram -> single-block scan -> scatter
// ===========================================================================
__global__ __launch_bounds__(256)
void hist_kernel(const int* __restrict__ dst, int* __restrict__ cnt, int E)
{
    const int e = blockIdx.x * 256 + threadIdx.x;
    if (e < E) atomicAdd(&cnt[dst[e]], 1);
}

__global__ __launch_bounds__(1024)
void scan_kernel(int* __restrict__ cnt, int NB)
{
    __shared__ int part[1024];
    const int t = threadIdx.x;
    const int CH = (NB + 1023) >> 10;
    const int base = t * CH;
    int s = 0;
    for (int k = 0; k < CH; ++k) { const int i = base + k; if (i < NB) s += cnt[i]; }
    part[t] = s;
    __syncthreads();
    for (int off = 1; off < 1024; off <<= 1) {
        const int add = (t >= off) ? part[t - off] : 0;
        __syncthreads();
        part[t] += add;
        __syncthreads();
    }
    int run = part[t] - s;
    for (int k = 0; k < CH; ++k) {
        const int i = base + k;
        if (i < NB) { const int c = cnt[i]; cnt[i] = run; run += c; }
    }
}

__global__ __launch_bounds__(256)
void scatter_kernel(const int* __restrict__ src, const int* __restrict__ dst,
                    const float* __restrict__ ea, int* __restrict__ cursor,
                    int* __restrict__ sSrc, int* __restrict__ sDst,
                    float* __restrict__ eaS, int E)
{
    const int e = blockIdx.x * 256 + threadIdx.x;
    if (e >= E) return;
    const int d = dst[e];
    const int p = atomicAdd(&cursor[d], 1);
    sSrc[p] = src[e];
    sDst[p] = d;
    ((float4*)eaS)[p] = ((const float4*)ea)[e];
}

// ===========================================================================
// MFMA GEMM over an LDS row-tile: one wave computes 16 rows x 128 cols.
// ===========================================================================
template<int KP, int FSTR, int NOUT, bool BIAS>
DEV void mfma_gemm(const short* aLds, const short* __restrict__ Wpk,
                   const float* __restrict__ b, int row0, int c0, int lane,
                   f32x4 (&acc)[8])
{
    const int l15 = lane & 15;
    const int lg  = lane >> 4;
#pragma unroll
    for (int f = 0; f < 8; ++f) {
        if (BIAS) {
            const float bv = b[c0 + f * 16 + l15];
            acc[f] = (f32x4){bv, bv, bv, bv};
        } else {
            acc[f] = (f32x4){0.f, 0.f, 0.f, 0.f};
        }
    }
    const short* arow  = aLds + (row0 + l15) * FSTR + lg * 8;
    const short* wbase = Wpk + (size_t)(c0 + l15) * 32 + lg * 8;
#pragma unroll
    for (int ks = 0; ks < KP / 32; ++ks) {
        const bf16x8 av = *(const bf16x8*)(arow + ks * 32);
        const short* wp = wbase + (size_t)ks * NOUT * 32;
#pragma unroll
        for (int f = 0; f < 8; ++f) {
            const bf16x8 bv = *(const bf16x8*)(wp + f * 512);
            acc[f] = __builtin_amdgcn_mfma_f32_16x16x32_bf16(av, bv, acc[f], 0, 0, 0);
        }
    }
}

// relu(acc [+ lds]) -> packed bf16 rows in LDS (plain row-major columns)
template<int OSTR, bool ADDLDS>
DEV void pack_relu(const f32x4 (&acc)[8], short* out, int row0, int c0, int lane)
{
    const int l15 = lane & 15;
    const int lg  = lane >> 4;
#pragma unroll
    for (int f = 0; f < 8; ++f)
#pragma unroll
        for (int i = 0; i < 4; ++i) {
            const int row = row0 + lg * 4 + i;
            const int col = c0 + f * 16 + l15;
            float vv = acc[f][i];
            if (ADDLDS) vv += bf2f(out[row * OSTR + col]);
            vv = fmaxf(vv, 0.0f);
            const float o = __shfl_xor(vv, 1);
            if (!(lane & 1)) {
                const unsigned pk = ((unsigned)(unsigned short)f2bf(o) << 16) |
                                    (unsigned)(unsigned short)f2bf(vv);
                *(unsigned*)&out[row * OSTR + col] = pk;
            }
        }
}

// ===========================================================================
// Per-node precompute: u = x@(W1a-W1b)+b1, v = x@W1b, sq = ||x||^2
// 64 nodes/block, 4 waves.
// ===========================================================================
template<int FIN, int FSTR>
__global__ __launch_bounds__(256)
void uv_pre(const float* __restrict__ xin,
            const short* __restrict__ Wd, const float* __restrict__ b1,
            const short* __restrict__ Wb,
            float* __restrict__ u, float* __restrict__ v, float* __restrict__ sq,
            int N)
{
    __shared__ __align__(16) short feat[64 * FSTR];
    const int tid = threadIdx.x, lane = tid & 63, wave = tid >> 6;
    const int n0 = blockIdx.x * 64;
    {
        const int r = tid >> 2, s = tid & 3, n = n0 + r;
        short* frow = feat + r * FSTR;
        if (n < N) {
            const float4* xr = (const float4*)(xin + (size_t)n * FIN);
            float ss = 0.f;
#pragma unroll
            for (int d4 = s; d4 < FIN / 4; d4 += 4) {
                const float4 a = xr[d4];
                ss += a.x * a.x + a.y * a.y + a.z * a.z + a.w * a.w;
                *(short4*)(frow + d4 * 4) =
                    make_short4(f2bf(a.x), f2bf(a.y), f2bf(a.z), f2bf(a.w));
            }
            ss += __shfl_xor(ss, 1); ss += __shfl_xor(ss, 2);
            if (s == 0) sq[n] = ss;
        } else {
            for (int d = s * 4; d < FIN; d += 16) *(short4*)(frow + d) = make_short4(0, 0, 0, 0);
        }
    }
    __syncthreads();
    const int l15 = lane & 15, lg = lane >> 4;
    f32x4 acc[8];
    mfma_gemm<FIN, FSTR, 128, true>(feat, Wd, b1, wave * 16, 0, lane, acc);
#pragma unroll
    for (int f = 0; f < 8; ++f)
#pragma unroll
        for (int i = 0; i < 4; ++i) {
            const int n = n0 + wave * 16 + lg * 4 + i;
            if (n < N) u[(size_t)n * 128 + f * 16 + l15] = acc[f][i];
        }
    mfma_gemm<FIN, FSTR, 128, false>(feat, Wb, nullptr, wave * 16, 0, lane, acc);
#pragma unroll
    for (int f = 0; f < 8; ++f)
#pragma unroll
        for (int i = 0; i < 4; ++i) {
            const int n = n0 + wave * 16 + lg * 4 + i;
            if (n < N) v[(size_t)n * 128 + f * 16 + l15] = acc[f][i];
        }
}

// ===========================================================================
// Edge conv (decomposed): 64 edges/block, 4 waves.
// h1 = relu( p@Wp + u[dst] + v[src] + e1*wt0 + e2*wt1 + ea@wt2..5 )
// m  = relu( h1@W2 + b2 ); run-max over sorted dst -> atomicMax.
// ===========================================================================
template<int FIN, int KPP, int FSTR>
__global__ __launch_bounds__(256)
void edge_conv2(const float* __restrict__ x,
                const int* __restrict__ sSrc, const int* __restrict__ sDst,
                const float* __restrict__ eaS, const float* __restrict__ sq,
                const float* __restrict__ u, const float* __restrict__ v,
                const float* __restrict__ w1tail,   // 6*128 f32 (rows e1,e2,ea0..3)
                const short* __restrict__ Wp, const short* __restrict__ W2,
                const float* __restrict__ b2,
                float* __restrict__ agg, int E)
{
    constexpr int H1STR = 136;
    __shared__ __align__(16) short sh[64 * FSTR + 64 * H1STR];
    __shared__ __align__(16) float wt[6 * 128];
    __shared__ int dstv[64];
    short* feat = sh;
    short* h1s  = sh + 64 * FSTR;
    const int tid = threadIdx.x, lane = tid & 63, wave = tid >> 6;
    const int e0 = blockIdx.x * 64;

    for (int i = tid; i < 768; i += 256) wt[i] = w1tail[i];
    __syncthreads();

    // ---- stage 1: p features + uv row (4 threads per edge) ----
    {
        const int r = tid >> 2, s = tid & 3, e = e0 + r;
        short* frow = feat + r * FSTR;
        short* urow = h1s + r * H1STR;
        if (e < E) {
            const int si = sSrc[e], di = sDst[e];
            if (s == 0) dstv[r] = di;
            const float4* xs = (const float4*)(x + (size_t)si * FIN);
            const float4* xd = (const float4*)(x + (size_t)di * FIN);
            float sp = 0.f;
#pragma unroll
            for (int d4 = s; d4 < FIN / 4; d4 += 4) {
                const float4 a = xs[d4], b = xd[d4];
                const float px = a.x * b.x, py = a.y * b.y, pz = a.z * b.z, pw = a.w * b.w;
                sp += px + py + pz + pw;
                *(short4*)(frow + d4 * 4) =
                    make_short4(f2bf(px), f2bf(py), f2bf(pz), f2bf(pw));
            }
            sp += __shfl_xor(sp, 1); sp += __shfl_xor(sp, 2);
            const float e2 = sp;
            const float e1 = sqrtf(fmaxf(sq[si] + sq[di] - 2.f * e2, 0.f));
            const float4 ea4 = *(const float4*)(eaS + (size_t)e * 4);
            const float4* ud = (const float4*)(u + (size_t)di * 128);
            const float4* vs = (const float4*)(v + (size_t)si * 128);
#pragma unroll
            for (int d4 = s; d4 < 32; d4 += 4) {
                const float4 uu = ud[d4], vv = vs[d4];
                const int c = d4 * 4;
                float o0 = uu.x + vv.x, o1 = uu.y + vv.y, o2 = uu.z + vv.z, o3 = uu.w + vv.w;
                o0 += e1 * wt[c]     + e2 * wt[128 + c]     + ea4.x * wt[256 + c]     + ea4.y * wt[384 + c]     + ea4.z * wt[512 + c]     + ea4.w * wt[640 + c];
                o1 += e1 * wt[c + 1] + e2 * wt[128 + c + 1] + ea4.x * wt[256 + c + 1] + ea4.y * wt[384 + c + 1] + ea4.z * wt[512 + c + 1] + ea4.w * wt[640 + c + 1];
                o2 += e1 * wt[c + 2] + e2 * wt[128 + c + 2] + ea4.x * wt[256 + c + 2] + ea4.y * wt[384 + c + 2] + ea4.z * wt[512 + c + 2] + ea4.w * wt[640 + c + 2];
                o3 += e1 * wt[c + 3] + e2 * wt[128 + c + 3] + ea4.x * wt[256 + c + 3] + ea4.y * wt[384 + c + 3] + ea4.z * wt[512 + c + 3] + ea4.w * wt[640 + c + 3];
                *(short4*)(urow + c) = make_short4(f2bf(o0), f2bf(o1), f2bf(o2), f2bf(o3));
            }
        } else {
            if (s == 0) dstv[r] = -1;
            for (int d = s * 4; d < KPP; d += 16) *(short4*)(frow + d) = make_short4(0, 0, 0, 0);
            for (int d = s * 4; d < 128; d += 16) *(short4*)(urow + d) = make_short4(0, 0, 0, 0);
        }
    }
    __syncthreads();

    f32x4 acc[8];
    // ---- stage 2: h1 = relu(p@Wp + uv) ----
    mfma_gemm<KPP, FSTR, 128, false>(feat, Wp, nullptr, wave * 16, 0, lane, acc);
    pack_relu<H1STR, true>(acc, h1s, wave * 16, 0, lane);
    __syncthreads();
    // ---- stage 3: m = relu(h1@W2 + b2) ----
    mfma_gemm<128, H1STR, 128, true>(h1s, W2, b2, wave * 16, 0, lane, acc);
    __syncthreads();                       // all h1s reads done -> reuse sh
    short* mbuf = sh;                      // [64][132] bf16
    pack_relu<132, false>(acc, mbuf, wave * 16, 0, lane);
    __syncthreads();

    // ---- stage 4: run-max over sorted dst ----
    {
        const int c  = tid >> 1;
        const int rh = tid & 1;
        int cur = -1;
        float mx = 0.0f;
#pragma unroll 4
        for (int i2 = 0; i2 < 32; ++i2) {
            const int row = rh * 32 + i2;
            const int d = dstv[row];
            const float val = bf2f(mbuf[row * 132 + c]);
            if (d != cur) {
                if (cur >= 0)
                    atomicMax((int*)agg + (size_t)cur * 128 + c, __float_as_int(mx));
                cur = d;
                mx = val;
            } else {
                mx = fmaxf(mx, val);
            }
        }
        if (cur >= 0)
            atomicMax((int*)agg + (size_t)cur * 128 + c, __float_as_int(mx));
    }
}

// ===========================================================================
// Node MLP (MFMA): y = relu(relu([x,agg]@W1+b1)@W2+b2) (+x if RES).
// ===========================================================================
template<int FIN, int KP, int FSTR, bool RES>
__global__ __launch_bounds__(256)
void node_mfma(const float* __restrict__ xin, const float* __restrict__ agg,
               const short* __restrict__ W1pk, const float* __restrict__ b1,
               const short* __restrict__ W2pk, const float* __restrict__ b2,
               float* __restrict__ out, int N)
{
    constexpr int H1STR = 136;
    __shared__ __align__(16) short sh[64 * FSTR + 64 * H1STR];
    short* feat = sh;
    short* h1s  = sh + 64 * FSTR;
    const int tid = threadIdx.x, lane = tid & 63, wave = tid >> 6;
    const int n0 = blockIdx.x * 64;

    {
        const int r = tid >> 2, s = tid & 3, n = n0 + r;
        short* frow = feat + r * FSTR;
        if (n < N) {
            const float4* xr = (const float4*)(xin + (size_t)n * FIN);
            const float4* ar = (const float4*)(agg + (size_t)n * 128);
#pragma unroll
            for (int d4 = s; d4 < FIN / 4; d4 += 4) {
                const float4 v = xr[d4];
                *(short4*)(frow + d4 * 4) = make_short4(f2bf(v.x), f2bf(v.y), f2bf(v.z), f2bf(v.w));
            }
#pragma unroll
            for (int d4 = s; d4 < 32; d4 += 4) {
                const float4 v = ar[d4];
                *(short4*)(frow + FIN + d4 * 4) = make_short4(f2bf(v.x), f2bf(v.y), f2bf(v.z), f2bf(v.w));
            }
        } else {
            for (int d = s * 4; d < KP; d += 16) *(short4*)(frow + d) = make_short4(0, 0, 0, 0);
        }
    }
    __syncthreads();

    f32x4 acc[8];
    mfma_gemm<KP, FSTR, 128, true>(feat, W1pk, b1, wave * 16, 0, lane, acc);
    pack_relu<H1STR, false>(acc, h1s, wave * 16, 0, lane);
    __syncthreads();
    mfma_gemm<128, H1STR, 128, true>(h1s, W2pk, b2, wave * 16, 0, lane, acc);
    {
        const int l15 = lane & 15, lg = lane >> 4;
#pragma unroll
        for (int f = 0; f < 8; ++f)
#pragma unroll
            for (int i = 0; i < 4; ++i) {
                const int n = n0 + wave * 16 + lg * 4 + i;
                if (n < N) {
                    const int c = f * 16 + l15;
                    float v = fmaxf(acc[f][i], 0.0f);
                    if (RES) v += xin[(size_t)n * 128 + c];
                    out[(size_t)n * 128 + c] = v;
                }
            }
    }
}

// ===========================================================================
// Fusion MLP (MFMA): out = relu(relu([x1,x2,x3]@W1+b1)@W2+b2).
// ===========================================================================
__global__ __launch_bounds__(128)
void fusion_mfma(const float* __restrict__ x1, const float* __restrict__ x2,
                 const float* __restrict__ x3,
                 const short* __restrict__ W1pk, const float* __restrict__ b1,
                 const short* __restrict__ W2pk, const float* __restrict__ b2,
                 float* __restrict__ out, int N)
{
    constexpr int FSTR = 392;
    constexpr int H1STR = 264;
    __shared__ __align__(16) short sh[32 * FSTR + 32 * H1STR];
    short* feat = sh;
    short* h1s  = sh + 32 * FSTR;
    const int tid = threadIdx.x, lane = tid & 63, wave = tid >> 6;
    const int n0 = blockIdx.x * 32;

    {
        const int r = tid >> 2, s = tid & 3, n = n0 + r;
        short* frow = feat + r * FSTR;
        if (n < N) {
            const float4* a1 = (const float4*)(x1 + (size_t)n * 128);
            const float4* a2 = (const float4*)(x2 + (size_t)n * 128);
            const float4* a3 = (const float4*)(x3 + (size_t)n * 128);
#pragma unroll
            for (int d4 = s; d4 < 32; d4 += 4) {
                const float4 v1 = a1[d4], v2 = a2[d4], v3 = a3[d4];
                *(short4*)(frow + d4 * 4)       = make_short4(f2bf(v1.x), f2bf(v1.y), f2bf(v1.z), f2bf(v1.w));
                *(short4*)(frow + 128 + d4 * 4) = make_short4(f2bf(v2.x), f2bf(v2.y), f2bf(v2.z), f2bf(v2.w));
                *(short4*)(frow + 256 + d4 * 4) = make_short4(f2bf(v3.x), f2bf(v3.y), f2bf(v3.z), f2bf(v3.w));
            }
        } else {
            for (int d = s * 4; d < 384; d += 16) *(short4*)(frow + d) = make_short4(0, 0, 0, 0);
        }
    }
    __syncthreads();

    f32x4 acc[8];
#pragma unroll
    for (int c0 = 0; c0 < 256; c0 += 128) {
        mfma_gemm<384, FSTR, 256, true>(feat, W1pk, b1, wave * 16, c0, lane, acc);
        pack_relu<H1STR, false>(acc, h1s, wave * 16, c0, lane);
    }
    __syncthreads();
    mfma_gemm<256, H1STR, 128, true>(h1s, W2pk, b2, wave * 16, 0, lane, acc);
    {
        const int l15 = lane & 15, lg = lane >> 4;
#pragma unroll
        for (int f = 0; f < 8; ++f)
#pragma unroll
            for (int i = 0; i < 4; ++i) {
                const int n = n0 + wave * 16 + lg * 4 + i;
                if (n < N)
                    out[(size_t)n * 128 + f * 16 + l15] = fmaxf(acc[f][i], 0.0f);
            }
    }
}

// ===========================================================================
extern "C" void kernel_launch(void* const* d_in, const int* in_sizes, int n_in,
                              void* d_out, int out_size, void* d_ws, size_t ws_size,
                              hipStream_t stream)
{
    const float* x    = (const float*)d_in[0];
    const int*   eidx = (const int*)d_in[1];
    const float* ea   = (const float*)d_in[2];

    const float* c1_eW1 = (const float*)d_in[3];
    const float* c1_eb1 = (const float*)d_in[4];
    const float* c1_eW2 = (const float*)d_in[5];
    const float* c1_eb2 = (const float*)d_in[6];
    const float* c1_lW1 = (const float*)d_in[7];
    const float* c1_lb1 = (const float*)d_in[8];
    const float* c1_lW2 = (const float*)d_in[9];
    const float* c1_lb2 = (const float*)d_in[10];

    const float* c2_eW1 = (const float*)d_in[11];
    const float* c2_eb1 = (const float*)d_in[12];
    const float* c2_eW2 = (const float*)d_in[13];
    const float* c2_eb2 = (const float*)d_in[14];
    const float* c2_lW1 = (const float*)d_in[15];
    const float* c2_lb1 = (const float*)d_in[16];
    const float* c2_lW2 = (const float*)d_in[17];
    const float* c2_lb2 = (const float*)d_in[18];

    const float* c3_eW1 = (const float*)d_in[19];
    const float* c3_eb1 = (const float*)d_in[20];
    const float* c3_eW2 = (const float*)d_in[21];
    const float* c3_eb2 = (const float*)d_in[22];
    const float* c3_lW1 = (const float*)d_in[23];
    const float* c3_lb1 = (const float*)d_in[24];
    const float* c3_lW2 = (const float*)d_in[25];
    const float* c3_lb2 = (const float*)d_in[26];

    const float* fus_W1 = (const float*)d_in[27];
    const float* fus_b1 = (const float*)d_in[28];
    const float* fus_W2 = (const float*)d_in[29];
    const float* fus_b2 = (const float*)d_in[30];

    const int N = in_sizes[0] / 32;   // 25000
    const int E = in_sizes[1] / 2;    // 400000
    const int* srcI = eidx;
    const int* dstI = eidx + E;

    const size_t NP = (size_t)N * 128;
    float* ws  = (float*)d_ws;
    float* x1  = ws;
    float* x2  = x1 + NP;
    float* x3  = x2 + NP;
    float* agg = x3 + NP;
    float* u   = agg + NP;
    float* v   = u + NP;
    float* sq  = v + NP;
    float* eaS = sq + N;
    int* cursor = (int*)(eaS + (size_t)E * 4);
    int* sSrc   = cursor + 25024;
    int* sDst   = sSrc + E;
    short* wpk  = (short*)(sDst + E);

    // packed-weight offsets (shorts)
    short* e1Wd = wpk + 0;
    short* e1Wb = wpk + 4096;
    short* e1Wp = wpk + 8192;
    short* e1W2 = wpk + 12288;
    short* e2Wd = wpk + 28672;
    short* e2Wb = wpk + 45056;
    short* e2Wp = wpk + 61440;
    short* e2W2 = wpk + 77824;
    short* e3Wd = wpk + 94208;
    short* e3Wb = wpk + 110592;
    short* e3Wp = wpk + 126976;
    short* e3W2 = wpk + 143360;
    short* n1W1 = wpk + 159744;
    short* n1W2 = wpk + 180224;
    short* n2W1 = wpk + 196608;
    short* n2W2 = wpk + 229376;
    short* n3W1 = wpk + 245760;
    short* n3W2 = wpk + 278528;
    short* fW1  = wpk + 294912;
    short* fW2  = wpk + 393216;
    const int packTotal = 425984;

    PackJobs pj;
    const float* pw[NPACK] = {
        c1_eW1, c1_eW1 + 32 * 128, c1_eW1 + 64 * 128, c1_eW2,
        c2_eW1, c2_eW1 + 128 * 128, c2_eW1 + 256 * 128, c2_eW2,
        c3_eW1, c3_eW1 + 128 * 128, c3_eW1 + 256 * 128, c3_eW2,
        c1_lW1, c1_lW2, c2_lW1, c2_lW2, c3_lW1, c3_lW2,
        fus_W1, fus_W2};
    const float* ps[NPACK] = {
        c1_eW1 + 32 * 128, nullptr, nullptr, nullptr,
        c2_eW1 + 128 * 128, nullptr, nullptr, nullptr,
        c3_eW1 + 128 * 128, nullptr, nullptr, nullptr,
        nullptr, nullptr, nullptr, nullptr, nullptr, nullptr,
        nullptr, nullptr};
    const int pk_kin[NPACK]  = {32, 32, 32, 128, 128, 128, 128, 128,
                                128, 128, 128, 128, 160, 128, 256, 128, 256, 128,
                                384, 256};
    const int pk_nout[NPACK] = {128, 128, 128, 128, 128, 128, 128, 128,
                                128, 128, 128, 128, 128, 128, 128, 128, 128, 128,
                                256, 128};
    const int pk_end[NPACK]  = {4096, 8192, 12288, 28672, 45056, 61440, 77824, 94208,
                                110592, 126976, 143360, 159744, 180224, 196608, 229376,
                                245760, 278528, 294912, 393216, 425984};
    for (int i = 0; i < NPACK; ++i) {
        pj.W[i] = pw[i]; pj.Wsub[i] = ps[i];
        pj.KIN[i] = pk_kin[i]; pj.NOUT[i] = pk_nout[i]; pj.end[i] = pk_end[i];
    }
    pack_all<<<(packTotal + 255) / 256, 256, 0, stream>>>(pj, wpk, packTotal);

    // ---- sort edges by dst ----
    const int eblk = (E + 255) / 256;
    hipMemsetAsync(cursor, 0, 25024 * sizeof(int), stream);
    hist_kernel<<<eblk, 256, 0, stream>>>(dstI, cursor, E);
    scan_kernel<<<1, 1024, 0, stream>>>(cursor, N);
    scatter_kernel<<<eblk, 256, 0, stream>>>(srcI, dstI, ea, cursor, sSrc, sDst, eaS, E);

    const int eblocks = (E + 63) / 64;
    const int nblocks = (N + 63) / 64;
    const int fblocks = (N + 31) / 32;
    const size_t aggBytes = NP * sizeof(float);

    // ---- layer 1 (FIN=32) ----
    uv_pre<32, 40><<<nblocks, 256, 0, stream>>>(x, e1Wd, c1_eb1, e1Wb, u, v, sq, N);
    hipMemsetAsync(agg, 0, aggBytes, stream);
    edge_conv2<32, 32, 40><<<eblocks, 256, 0, stream>>>(
        x, sSrc, sDst, eaS, sq, u, v, c1_eW1 + 96 * 128, e1Wp, e1W2, c1_eb2, agg, E);
    node_mfma<32, 160, 168, false><<<nblocks, 256, 0, stream>>>(
        x, agg, n1W1, c1_lb1, n1W2, c1_lb2, x1, N);

    // ---- layer 2 (FIN=128, residual) ----
    uv_pre<128, 136><<<nblocks, 256, 0, stream>>>(x1, e2Wd, c2_eb1, e2Wb, u, v, sq, N);
    hipMemsetAsync(agg, 0, aggBytes, stream);
    edge_conv2<128, 128, 136><<<eblocks, 256, 0, stream>>>(
        x1, sSrc, sDst, eaS, sq, u, v, c2_eW1 + 384 * 128, e2Wp, e2W2, c2_eb2, agg, E);
    node_mfma<128, 256, 264, true><<<nblocks, 256, 0, stream>>>(
        x1, agg, n2W1, c2_lb1, n2W2, c2_lb2, x2, N);

    // ---- layer 3 (FIN=128, residual) ----
    uv_pre<128, 136><<<nblocks, 256, 0, stream>>>(x2, e3Wd, c3_eb1, e3Wb, u, v, sq, N);
    hipMemsetAsync(agg, 0, aggBytes, stream);
    edge_conv2<128, 128, 136><<<eblocks, 256, 0, stream>>>(
        x2, sSrc, sDst, eaS, sq, u, v, c3_eW1 + 384 * 128, e3Wp, e3W2, c3_eb2, agg, E);
    node_mfma<128, 256, 264, true><<<nblocks, 256, 0, stream>>>(
        x2, agg, n3W1, c3_lb1, n3W2, c3_lb2, x3, N);

    // ---- fusion ----
    fusion_mfma<<<fblocks, 128, 0, stream>>>(
        x1, x2, x3, fW1, fus_b1, fW2, fus_b2, (float*)d_out, N);
}